// Round 2
// baseline (239.335 us; speedup 1.0000x reference)
//
#include <hip/hip_runtime.h>
#include <hip/hip_bf16.h>

// ---- problem constants ----
#define IN_F   3072
#define OUT_F  12288
#define M_ROWS 64
#define NBLK   96            // IN_F / 32
#define SPLITK 4
#define KCHUNK (IN_F / SPLITK)   // 768
#define KSTEPS (KCHUNK / 32)     // 24
#define OUT_ELEMS (M_ROWS * OUT_F)   // 786432

typedef short bf16x8 __attribute__((ext_vector_type(8)));   // 8 bf16 = 4 VGPRs
typedef float f32x4  __attribute__((ext_vector_type(4)));

__device__ __forceinline__ short f2bf(float f) {
    __hip_bfloat16 h = __float2bfloat16(f);
    union { __hip_bfloat16 h; short s; } u;
    u.h = h;
    return u.s;
}

// Pack x (64 x 3072 f32) into MFMA A-fragment order, bf16.
// Fragment index p = (ks_global*4 + mt)*64 + lane; lane holds
// x[mt*16 + (lane&15)][ks*32 + (lane>>4)*8 + j], j=0..7.
__global__ void pack_x(const float* __restrict__ x, short* __restrict__ xp) {
    int p   = blockIdx.x * 256 + threadIdx.x;   // 0..24575
    int ks  = p >> 8;                           // 0..95
    int rem = p & 255;
    int mt  = rem >> 6;
    int l   = rem & 63;
    int m   = mt * 16 + (l & 15);
    int k0  = ks * 32 + (l >> 4) * 8;
    const float4* src = reinterpret_cast<const float4*>(x + m * IN_F + k0);
    float4 a = src[0];
    float4 b = src[1];
    bf16x8 v;
    v[0] = f2bf(a.x); v[1] = f2bf(a.y); v[2] = f2bf(a.z); v[3] = f2bf(a.w);
    v[4] = f2bf(b.x); v[5] = f2bf(b.y); v[6] = f2bf(b.z); v[7] = f2bf(b.w);
    *reinterpret_cast<bf16x8*>(xp + (long)p * 8) = v;
}

// Fallback path: init out with bias, gemm atomically accumulates.
__global__ void init_out(const int* __restrict__ bq, const float* __restrict__ bs,
                         float* __restrict__ out) {
    int o = blockIdx.x * 256 + threadIdx.x;   // 0..12287
    int m = blockIdx.y;                       // 0..63
    float bias = (float)(bq[o] - 128) * bs[o >> 5];
    out[m * OUT_F + o] = bias;
}

// Final reduce for the partials path: out = sum of 4 split-K partials + bias.
__global__ void reduce_bias(const float* __restrict__ part,
                            const int* __restrict__ bq, const float* __restrict__ bs,
                            float* __restrict__ out) {
    int o = blockIdx.x * 256 + threadIdx.x;   // 0..12287
    int m = blockIdx.y;                       // 0..63
    int idx = m * OUT_F + o;
    float bias = (float)(bq[o] - 128) * bs[o >> 5];
    float s = bias
            + part[idx]
            + part[idx + OUT_ELEMS]
            + part[idx + 2 * OUT_ELEMS]
            + part[idx + 3 * OUT_ELEMS];
    out[idx] = s;
}

// Main GEMM. Block = 4 waves; wave -> 16 output cols x 64 rows, one split-K
// chunk of 768. grid = (12288/64) * 4 = 768 blocks = exactly 3 per CU.
__global__ __launch_bounds__(256) void gemm(const int*   __restrict__ wq,
                                            const float* __restrict__ wsc,
                                            const short* __restrict__ xp,
                                            float*       __restrict__ out,
                                            float*       __restrict__ part,
                                            int use_part) {
    __shared__ float s_sc[64 * 25];   // 64 rows x 24 k-blocks, padded to 25 (bank-conflict-free)

    int tid  = threadIdx.x;
    int bid  = blockIdx.x;
    int kc   = bid & 3;        // split-K chunk
    int colg = bid >> 2;       // 0..191, 64-col group
    int wave = tid >> 6;
    int l    = tid & 63;
    int ro   = l & 15;         // col within 16-wide tile / A row within tile
    int kq   = l >> 4;         // k-quad

    // Stage this block's scales: rows [colg*64, +64), k-blocks [kc*24, +24)
    for (int i = tid; i < 64 * KSTEPS; i += 256) {
        int r = i / KSTEPS;
        int c = i - r * KSTEPS;
        s_sc[r * 25 + c] = wsc[(colg * 64 + r) * NBLK + kc * KSTEPS + c];
    }
    __syncthreads();

    int col_base = colg * 64 + wave * 16;
    const int*   wrow  = wq + (col_base + ro) * IN_F + kc * KCHUNK + kq * 8;
    // fragment element offset = ks_global*2048 + mt*512 + lane*8
    const short* xbase = xp + ((long)(kc * KSTEPS) * 2048 + (long)l * 8);
    const float* scp   = &s_sc[(wave * 16 + ro) * 25];

    f32x4 acc[4] = {f32x4{0.f,0.f,0.f,0.f}, f32x4{0.f,0.f,0.f,0.f},
                    f32x4{0.f,0.f,0.f,0.f}, f32x4{0.f,0.f,0.f,0.f}};

    // ---- register double-buffered K loop ----
    int4   qa, qb;
    bf16x8 xa[4];
    qa = *reinterpret_cast<const int4*>(wrow);
    qb = *reinterpret_cast<const int4*>(wrow + 4);
#pragma unroll
    for (int mt = 0; mt < 4; ++mt)
        xa[mt] = *reinterpret_cast<const bf16x8*>(xbase + mt * 512);

#pragma unroll
    for (int ks = 0; ks < KSTEPS; ++ks) {
        int4   qa_n, qb_n;
        bf16x8 xa_n[4];
        if (ks + 1 < KSTEPS) {
            const int* wn = wrow + (ks + 1) * 32;
            qa_n = *reinterpret_cast<const int4*>(wn);
            qb_n = *reinterpret_cast<const int4*>(wn + 4);
            const short* xn = xbase + (long)(ks + 1) * 2048;
#pragma unroll
            for (int mt = 0; mt < 4; ++mt)
                xa_n[mt] = *reinterpret_cast<const bf16x8*>(xn + mt * 512);
        }

        float sc = scp[ks];
        bf16x8 bfrag;
        bfrag[0] = f2bf((float)(qa.x - 128) * sc);
        bfrag[1] = f2bf((float)(qa.y - 128) * sc);
        bfrag[2] = f2bf((float)(qa.z - 128) * sc);
        bfrag[3] = f2bf((float)(qa.w - 128) * sc);
        bfrag[4] = f2bf((float)(qb.x - 128) * sc);
        bfrag[5] = f2bf((float)(qb.y - 128) * sc);
        bfrag[6] = f2bf((float)(qb.z - 128) * sc);
        bfrag[7] = f2bf((float)(qb.w - 128) * sc);

#pragma unroll
        for (int mt = 0; mt < 4; ++mt)
            acc[mt] = __builtin_amdgcn_mfma_f32_16x16x32_bf16(xa[mt], bfrag, acc[mt], 0, 0, 0);

        if (ks + 1 < KSTEPS) {
            qa = qa_n; qb = qb_n;
#pragma unroll
            for (int mt = 0; mt < 4; ++mt) xa[mt] = xa_n[mt];
        }
    }

    // ---- epilogue: D col = lane&15, row = (lane>>4)*4 + reg ----
    if (use_part) {
        float* dst = part + (long)kc * OUT_ELEMS;
#pragma unroll
        for (int mt = 0; mt < 4; ++mt) {
            int mrow = mt * 16 + kq * 4;
#pragma unroll
            for (int r = 0; r < 4; ++r)
                dst[(mrow + r) * OUT_F + col_base + ro] = acc[mt][r];
        }
    } else {
#pragma unroll
        for (int mt = 0; mt < 4; ++mt) {
            int mrow = mt * 16 + kq * 4;
#pragma unroll
            for (int r = 0; r < 4; ++r)
                atomicAdd(out + (mrow + r) * OUT_F + col_base + ro, acc[mt][r]);
        }
    }
}

extern "C" void kernel_launch(void* const* d_in, const int* in_sizes, int n_in,
                              void* d_out, int out_size, void* d_ws, size_t ws_size,
                              hipStream_t stream) {
    const float* x   = (const float*)d_in[0];
    const int*   wq  = (const int*)d_in[1];
    const float* wsc = (const float*)d_in[2];
    const int*   bq  = (const int*)d_in[3];
    const float* bs  = (const float*)d_in[4];
    float* out = (float*)d_out;

    short* xp   = (short*)d_ws;                         // 393216 B
    float* part = (float*)((char*)d_ws + 393216);       // 12582912 B
    const size_t WS_NEED = 393216 + (size_t)4 * OUT_ELEMS * sizeof(float);
    bool use_part = ws_size >= WS_NEED;

    pack_x<<<96, 256, 0, stream>>>(x, xp);
    if (use_part) {
        gemm<<<768, 256, 0, stream>>>(wq, wsc, xp, out, part, 1);
        reduce_bias<<<dim3(OUT_F / 256, M_ROWS), 256, 0, stream>>>(part, bq, bs, out);
    } else {
        init_out<<<dim3(OUT_F / 256, M_ROWS), 256, 0, stream>>>(bq, bs, out);
        gemm<<<768, 256, 0, stream>>>(wq, wsc, xp, out, nullptr, 0);
    }
}

// Round 3
// 235.404 us; speedup vs baseline: 1.0167x; 1.0167x over previous
//
#include <hip/hip_runtime.h>
#include <hip/hip_bf16.h>

// ---- problem constants ----
#define IN_F   3072
#define OUT_F  12288
#define M_ROWS 64
#define NBLK   96                // IN_F / 32
#define KCHUNK (IN_F / 4)        // 768  (per-wave split-K chunk)
#define KSTEPS (KCHUNK / 32)     // 24

typedef short bf16x8 __attribute__((ext_vector_type(8)));   // 8 bf16 = 4 VGPRs
typedef float f32x4  __attribute__((ext_vector_type(4)));

__device__ __forceinline__ short f2bf(float f) {
    __hip_bfloat16 h = __float2bfloat16(f);
    union { __hip_bfloat16 h; short s; } u;
    u.h = h;
    return u.s;
}

// Pack x (64 x 3072 f32) into MFMA A-fragment order, bf16.
// Fragment index p = (ks_global*4 + mt)*64 + lane; lane holds
// x[mt*16 + (lane&15)][ks*32 + (lane>>4)*8 + j], j=0..7.
__global__ void pack_x(const float* __restrict__ x, short* __restrict__ xp) {
    int p   = blockIdx.x * 256 + threadIdx.x;   // 0..24575
    int ks  = p >> 8;                           // 0..95
    int rem = p & 255;
    int mt  = rem >> 6;
    int l   = rem & 63;
    int m   = mt * 16 + (l & 15);
    int k0  = ks * 32 + (l >> 4) * 8;
    const float4* src = reinterpret_cast<const float4*>(x + m * IN_F + k0);
    float4 a = src[0];
    float4 b = src[1];
    bf16x8 v;
    v[0] = f2bf(a.x); v[1] = f2bf(a.y); v[2] = f2bf(a.z); v[3] = f2bf(a.w);
    v[4] = f2bf(b.x); v[5] = f2bf(b.y); v[6] = f2bf(b.z); v[7] = f2bf(b.w);
    *reinterpret_cast<bf16x8*>(xp + (long)p * 8) = v;
}

// Fused GEMM: block = 16 output cols, 4 waves split K (768 each),
// LDS cross-wave reduce + bias + direct f32x4 store. grid = 768 blocks
// (= 3 blocks/CU, 12 waves/CU).
__global__ __launch_bounds__(256) void gemm(const int*   __restrict__ wq,
                                            const float* __restrict__ wsc,
                                            const short* __restrict__ xp,
                                            const int*   __restrict__ bq,
                                            const float* __restrict__ bs,
                                            float*       __restrict__ out) {
    __shared__ float s_sc[16 * 97];        // 16 cols x 96 k-blocks, pad 97
    __shared__ float s_red[4][64][17];     // per-wave partial C, pad 17

    int tid  = threadIdx.x;
    int cb   = blockIdx.x * 16;    // col base
    int wave = tid >> 6;           // = k-chunk index
    int l    = tid & 63;
    int ro   = l & 15;             // output col within tile
    int kq   = l >> 4;

    // Stage scales: 16 rows x 96 k-blocks
    for (int i = tid; i < 16 * NBLK; i += 256) {
        int r = i / NBLK;
        int c = i - r * NBLK;
        s_sc[r * 97 + c] = wsc[(cb + r) * NBLK + c];
    }
    __syncthreads();

    const int*   wrow  = wq + (cb + ro) * IN_F + wave * KCHUNK + kq * 8;
    // fragment element offset = ks_global*2048 + mt*512 + lane*8
    const short* xbase = xp + ((long)(wave * KSTEPS) * 2048 + (long)l * 8);
    const float* scp   = &s_sc[ro * 97 + wave * KSTEPS];

    f32x4 acc[4] = {f32x4{0.f,0.f,0.f,0.f}, f32x4{0.f,0.f,0.f,0.f},
                    f32x4{0.f,0.f,0.f,0.f}, f32x4{0.f,0.f,0.f,0.f}};

    // ---- register double-buffered K loop ----
    int4   qa, qb;
    bf16x8 xa[4];
    qa = *reinterpret_cast<const int4*>(wrow);
    qb = *reinterpret_cast<const int4*>(wrow + 4);
#pragma unroll
    for (int mt = 0; mt < 4; ++mt)
        xa[mt] = *reinterpret_cast<const bf16x8*>(xbase + mt * 512);

#pragma unroll
    for (int ks = 0; ks < KSTEPS; ++ks) {
        int4   qa_n, qb_n;
        bf16x8 xa_n[4];
        if (ks + 1 < KSTEPS) {
            const int* wn = wrow + (ks + 1) * 32;
            qa_n = *reinterpret_cast<const int4*>(wn);
            qb_n = *reinterpret_cast<const int4*>(wn + 4);
            const short* xn = xbase + (long)(ks + 1) * 2048;
#pragma unroll
            for (int mt = 0; mt < 4; ++mt)
                xa_n[mt] = *reinterpret_cast<const bf16x8*>(xn + mt * 512);
        }

        float sc = scp[ks];
        bf16x8 bfrag;
        bfrag[0] = f2bf((float)(qa.x - 128) * sc);
        bfrag[1] = f2bf((float)(qa.y - 128) * sc);
        bfrag[2] = f2bf((float)(qa.z - 128) * sc);
        bfrag[3] = f2bf((float)(qa.w - 128) * sc);
        bfrag[4] = f2bf((float)(qb.x - 128) * sc);
        bfrag[5] = f2bf((float)(qb.y - 128) * sc);
        bfrag[6] = f2bf((float)(qb.z - 128) * sc);
        bfrag[7] = f2bf((float)(qb.w - 128) * sc);

#pragma unroll
        for (int mt = 0; mt < 4; ++mt)
            acc[mt] = __builtin_amdgcn_mfma_f32_16x16x32_bf16(xa[mt], bfrag, acc[mt], 0, 0, 0);

        if (ks + 1 < KSTEPS) {
            qa = qa_n; qb = qb_n;
#pragma unroll
            for (int mt = 0; mt < 4; ++mt) xa[mt] = xa_n[mt];
        }
    }

    // ---- epilogue: D col = lane&15, row = (lane>>4)*4 + reg ----
    // Dump per-wave partials to LDS.
#pragma unroll
    for (int mt = 0; mt < 4; ++mt) {
        int mrow = mt * 16 + kq * 4;
#pragma unroll
        for (int r = 0; r < 4; ++r)
            s_red[wave][mrow + r][ro] = acc[mt][r];
    }
    __syncthreads();

    // Cross-wave reduce + bias: 256 threads -> 64 rows x 16 cols, 4 cols each.
    int row = tid >> 2;            // 0..63
    int c0  = (tid & 3) * 4;       // 0,4,8,12
    float4 v;
#pragma unroll
    for (int j = 0; j < 4; ++j) {
        int c = c0 + j;
        float s = s_red[0][row][c] + s_red[1][row][c]
                + s_red[2][row][c] + s_red[3][row][c];
        int col = cb + c;
        float bias = (float)(bq[col] - 128) * bs[col >> 5];
        (&v.x)[j] = s + bias;
    }
    *reinterpret_cast<float4*>(out + (long)row * OUT_F + cb + c0) = v;
}

extern "C" void kernel_launch(void* const* d_in, const int* in_sizes, int n_in,
                              void* d_out, int out_size, void* d_ws, size_t ws_size,
                              hipStream_t stream) {
    const float* x   = (const float*)d_in[0];
    const int*   wq  = (const int*)d_in[1];
    const float* wsc = (const float*)d_in[2];
    const int*   bq  = (const int*)d_in[3];
    const float* bs  = (const float*)d_in[4];
    float* out = (float*)d_out;

    short* xp = (short*)d_ws;   // 393216 B of ws

    pack_x<<<96, 256, 0, stream>>>(x, xp);
    gemm<<<OUT_F / 16, 256, 0, stream>>>(wq, wsc, xp, bq, bs, out);
}